// Round 15
// baseline (101.721 us; speedup 1.0000x reference)
//
#include <hip/hip_runtime.h>
#include <math.h>

#define N 3072
#define H 64
#define CAUS 16
#define CSD 32
#define GAT_ALPHA 0.35f
#define SLICES 8
#define JSL (N / SLICES)  // 384 (agg split)
#define MMS 16
#define JMM (N / MMS)     // 192 (mm/dec split)
#define NH (N * H)        // 196608
typedef unsigned long long u64;
typedef unsigned short u16;
typedef __attribute__((ext_vector_type(4))) float f32x4;
typedef __attribute__((ext_vector_type(8))) short s16x8;
struct alignas(8) u16x4 { u16 x, y, z, w; };
struct T4 { float4 r[4]; };

// f32 -> bf16 round-to-nearest-even
__device__ inline u16 f2bf(float f) {
  unsigned u = __builtin_bit_cast(unsigned, f);
  u += 0x7fffu + ((u >> 16) & 1u);
  return (u16)(u >> 16);
}

__device__ inline T4 t_load(const float* __restrict__ src, int ld, int t) {
  int k4 = (t >> 4) * 4, m4 = (t & 15) * 4;
  T4 o;
#pragma unroll
  for (int d = 0; d < 4; d++)
    o.r[d] = *(const float4*)(src + (size_t)(k4 + d) * ld + m4);
  return o;
}
__device__ inline void t_store(u16 (&dst)[64][72], const T4& v, int t) {
  int k4 = (t >> 4) * 4, m4 = (t & 15) * 4;
  u16x4 c0 = {f2bf(v.r[0].x), f2bf(v.r[1].x), f2bf(v.r[2].x), f2bf(v.r[3].x)};
  u16x4 c1 = {f2bf(v.r[0].y), f2bf(v.r[1].y), f2bf(v.r[2].y), f2bf(v.r[3].y)};
  u16x4 c2 = {f2bf(v.r[0].z), f2bf(v.r[1].z), f2bf(v.r[2].z), f2bf(v.r[3].z)};
  u16x4 c3 = {f2bf(v.r[0].w), f2bf(v.r[1].w), f2bf(v.r[2].w), f2bf(v.r[3].w)};
  *(u16x4*)&dst[m4 + 0][k4] = c0;
  *(u16x4*)&dst[m4 + 1][k4] = c1;
  *(u16x4*)&dst[m4 + 2][k4] = c2;
  *(u16x4*)&dst[m4 + 3][k4] = c3;
}

// ---------------------------------------------------------------------------
// Fused: blocks 0-767 = adjacency pack (first: starts adj stream during ramp);
// blocks 768-2303 = x^T@Wgat GEMM (32-gene, 16 K-slices, upfront loads,
// double-buffered LDS -> 3 barriers total).
__global__ __launch_bounds__(256) void k_mmpk(const float* __restrict__ x,
                                              const float* __restrict__ Wgat,
                                              float* __restrict__ part,
                                              const int* __restrict__ adj,
                                              u64* __restrict__ packed,
                                              float* __restrict__ dis) {
  __shared__ u16 As[2][32][72];
  __shared__ u16 Bs[2][64][72];
  int bid = blockIdx.x, t = threadIdx.x;
  if (bid < 768) {  // ---- pack branch
    int row = bid * 4 + (t >> 6), lane = t & 63;
    const int* ar = adj + (size_t)row * N;
    int deg = 0;
    for (int w0 = 0; w0 < 48; w0 += 8) {
      int vals[8];
#pragma unroll
      for (int q = 0; q < 8; q++) vals[q] = ar[(w0 + q) * 64 + lane];
#pragma unroll
      for (int q = 0; q < 8; q++) {
        u64 m = __ballot(vals[q] > 0);
        if (lane == 0) packed[(size_t)row * 48 + w0 + q] = m;
        deg += (vals[q] > 0) ? 1 : 0;
      }
    }
    for (int off = 32; off; off >>= 1) deg += __shfl_xor(deg, off);
    if (lane == 0) dis[row] = rsqrtf((float)deg + 1.0f);
    return;
  }
  // ---- GEMM branch
  int mb = bid - 768;
  int gx = mb % 96, sl = mb / 96;
  int g0 = gx * 32, c0 = sl * JMM;
  int w = t >> 6, l = t & 63, il = l & 15, kg = l >> 4;
  int ri = w & 1, cj = w >> 1;
  int ak = (t >> 3) * 2, am = (t & 7) * 4;
  float4 a0[3], a1[3];
  T4 bv[3];
#pragma unroll
  for (int it = 0; it < 3; it++) {
    a0[it] = *(const float4*)(x + (size_t)(c0 + it * 64 + ak) * N + g0 + am);
    a1[it] = *(const float4*)(x + (size_t)(c0 + it * 64 + ak + 1) * N + g0 + am);
    bv[it] = t_load(Wgat + (size_t)(c0 + it * 64) * H, H, t);
  }
  f32x4 acc0 = {0.f, 0.f, 0.f, 0.f}, acc1 = {0.f, 0.f, 0.f, 0.f};
  // stage iter 0 into buffer 0
  As[0][am + 0][ak] = f2bf(a0[0].x); As[0][am + 1][ak] = f2bf(a0[0].y);
  As[0][am + 2][ak] = f2bf(a0[0].z); As[0][am + 3][ak] = f2bf(a0[0].w);
  As[0][am + 0][ak + 1] = f2bf(a1[0].x); As[0][am + 1][ak + 1] = f2bf(a1[0].y);
  As[0][am + 2][ak + 1] = f2bf(a1[0].z); As[0][am + 3][ak + 1] = f2bf(a1[0].w);
  t_store(Bs[0], bv[0], t);
  int cur = 0;
#pragma unroll
  for (int it = 0; it < 3; it++) {
    __syncthreads();  // buf[cur] stores visible; buf[cur^1] free (prev MFMA done)
    if (it < 2) {
      int nx = cur ^ 1;
      As[nx][am + 0][ak] = f2bf(a0[it + 1].x); As[nx][am + 1][ak] = f2bf(a0[it + 1].y);
      As[nx][am + 2][ak] = f2bf(a0[it + 1].z); As[nx][am + 3][ak] = f2bf(a0[it + 1].w);
      As[nx][am + 0][ak + 1] = f2bf(a1[it + 1].x); As[nx][am + 1][ak + 1] = f2bf(a1[it + 1].y);
      As[nx][am + 2][ak + 1] = f2bf(a1[it + 1].z); As[nx][am + 3][ak + 1] = f2bf(a1[it + 1].w);
      t_store(Bs[nx], bv[it + 1], t);
    }
#pragma unroll
    for (int kk = 0; kk < 64; kk += 32) {
      s16x8 a = *(const s16x8*)&As[cur][ri * 16 + il][kk + kg * 8];
      s16x8 b0 = *(const s16x8*)&Bs[cur][cj * 32 + il][kk + kg * 8];
      s16x8 b1 = *(const s16x8*)&Bs[cur][cj * 32 + 16 + il][kk + kg * 8];
      acc0 = __builtin_amdgcn_mfma_f32_16x16x32_bf16(a, b0, acc0, 0, 0, 0);
      acc1 = __builtin_amdgcn_mfma_f32_16x16x32_bf16(a, b1, acc1, 0, 0, 0);
    }
    cur ^= 1;
  }
  float* ob = part + (size_t)sl * NH;
#pragma unroll
  for (int c = 0; c < 2; c++) {
    f32x4 acc = c ? acc1 : acc0;
    int col = cj * 32 + c * 16 + il;
    int rbase = g0 + ri * 16 + kg * 4;
#pragma unroll
    for (int r = 0; r < 4; r++)
      ob[(size_t)(rbase + r) * H + col] = acc[r];
  }
}

// ---------------------------------------------------------------------------
// Split-K masked aggregation, 32-row tiles, grid (96,8), double-buffered LDS
// -> single barrier per j-tile (6 instead of 12).
template <int GAT>
__global__ __launch_bounds__(256) void k_agg(const float* __restrict__ hin,
                                             const u64* __restrict__ packed,
                                             const float* __restrict__ sdst,
                                             const float* __restrict__ ssrc,
                                             const float* __restrict__ dis,
                                             float* __restrict__ outp,
                                             float* __restrict__ zpart) {
  __shared__ u16 Ws[2][32][72];
  __shared__ u16 Hs[2][64][72];
  __shared__ float ssl[32];
  int t = threadIdx.x;
  int i0 = blockIdx.x * 32;
  int jbase = blockIdx.y * JSL;
  int w = t >> 6, l = t & 63, il = l & 15, kg = l >> 4;
  int ri = w & 1, cj = w >> 1;
  int r = t >> 3, jq = (t & 7) * 8;
  if (GAT && t < 32) ssl[t] = ssrc[i0 + t];
  if (GAT) __syncthreads();
  float sv = GAT ? ssl[r] : 0.f;
  float zacc = 0.f;
  f32x4 acc0 = {0.f, 0.f, 0.f, 0.f}, acc1 = {0.f, 0.f, 0.f, 0.f};

  auto gen_w = [&](int j0, float (&wv)[8]) {
    u64 wb = packed[(size_t)(i0 + r) * 48 + (j0 >> 6)];
    if (GAT) {
      const float4* s4p = (const float4*)(sdst + j0 + jq);
      float4 s0 = s4p[0], s1 = s4p[1];
      float sf[8] = {s0.x, s0.y, s0.z, s0.w, s1.x, s1.y, s1.z, s1.w};
#pragma unroll
      for (int q = 0; q < 8; q++) {
        float e = sv + sf[q];
        e = e > 0.f ? e : GAT_ALPHA * e;
        float ww = ((wb >> (jq + q)) & 1ULL) ? __expf(e) : 0.f;
        wv[q] = ww;
        zacc += ww;
      }
    } else {
      const float4* d4p = (const float4*)(dis + j0 + jq);
      float4 d0 = d4p[0], d1 = d4p[1];
      float df[8] = {d0.x, d0.y, d0.z, d0.w, d1.x, d1.y, d1.z, d1.w};
#pragma unroll
      for (int q = 0; q < 8; q++) {
        float cnt = (float)((wb >> (jq + q)) & 1ULL) +
                    ((i0 + r) == (j0 + jq + q) ? 1.f : 0.f);
        wv[q] = cnt * df[q];
      }
    }
  };
  auto stage = [&](int buf, const T4& hv, const float (&wv)[8]) {
    t_store(Hs[buf], hv, t);
    u16x4 w0 = {f2bf(wv[0]), f2bf(wv[1]), f2bf(wv[2]), f2bf(wv[3])};
    u16x4 w1 = {f2bf(wv[4]), f2bf(wv[5]), f2bf(wv[6]), f2bf(wv[7])};
    *(u16x4*)&Ws[buf][r][jq] = w0;
    *(u16x4*)&Ws[buf][r][jq + 4] = w1;
  };

  T4 hv = t_load(hin + (size_t)jbase * H, H, t);
  float wv[8];
  gen_w(jbase, wv);
  stage(0, hv, wv);
  int cur = 0;
  for (int jb = 0; jb < JSL; jb += 64) {
    bool more = (jb + 64 < JSL);
    if (more) {
      hv = t_load(hin + (size_t)(jbase + jb + 64) * H, H, t);
      gen_w(jbase + jb + 64, wv);
    }
    __syncthreads();  // buf[cur] visible; buf[cur^1] free
    if (more) stage(cur ^ 1, hv, wv);
#pragma unroll
    for (int kk = 0; kk < 64; kk += 32) {
      s16x8 a = *(const s16x8*)&Ws[cur][ri * 16 + il][kk + kg * 8];
      s16x8 b0 = *(const s16x8*)&Hs[cur][cj * 32 + il][kk + kg * 8];
      s16x8 b1 = *(const s16x8*)&Hs[cur][cj * 32 + 16 + il][kk + kg * 8];
      acc0 = __builtin_amdgcn_mfma_f32_16x16x32_bf16(a, b0, acc0, 0, 0, 0);
      acc1 = __builtin_amdgcn_mfma_f32_16x16x32_bf16(a, b1, acc1, 0, 0, 0);
    }
    cur ^= 1;
  }
  if (GAT) {
    zacc += __shfl_xor(zacc, 1);
    zacc += __shfl_xor(zacc, 2);
    zacc += __shfl_xor(zacc, 4);
    if ((t & 7) == 0) zpart[(size_t)blockIdx.y * N + i0 + r] = zacc;
  }
  float* ob = outp + (size_t)blockIdx.y * NH;
#pragma unroll
  for (int c = 0; c < 2; c++) {
    f32x4 acc = c ? acc1 : acc0;
    int col = cj * 32 + c * 16 + il;
    int rbase = i0 + ri * 16 + kg * 4;
#pragma unroll
    for (int rr = 0; rr < 4; rr++)
      ob[(size_t)(rbase + rr) * H + col] = acc[rr];
  }
}

// ---------------------------------------------------------------------------
// Fused decoder + GCN GEMM: 32-gene tiles, grid (96, 16), upfront K-loads.
__global__ __launch_bounds__(256) void k_dec32(const float* __restrict__ cs,
                                               const float* __restrict__ Wdec,
                                               const float* __restrict__ bdec,
                                               const float* __restrict__ Wg1,
                                               float* __restrict__ xr,
                                               float* __restrict__ outp) {
  __shared__ u16 As[32][72];
  __shared__ u16 Bs[64][72];
  __shared__ u16 Wd[32][40];
  __shared__ u16 Csh[64][40];
  __shared__ float bs_s[32];
  int t = threadIdx.x;
  int g0 = blockIdx.x * 32;
  int c0 = blockIdx.y * JMM;
  int w = t >> 6, l = t & 63, il = l & 15, kg = l >> 4;
  int ri = w & 1, cj = w >> 1;
  {
    int q = t >> 3, m4 = (t & 7) * 4;
    float4 v = *(const float4*)(Wdec + (size_t)q * N + g0 + m4);
    Wd[m4 + 0][q] = f2bf(v.x); Wd[m4 + 1][q] = f2bf(v.y);
    Wd[m4 + 2][q] = f2bf(v.z); Wd[m4 + 3][q] = f2bf(v.w);
    if (t < 32) bs_s[t] = bdec[g0 + t];
  }
  int cell = t >> 3, qf = (t & 7) * 4;
  float4 cv0[3], cv1[3];
  T4 bv[3];
#pragma unroll
  for (int it = 0; it < 3; it++) {
    cv0[it] = *(const float4*)(cs + (size_t)(c0 + it * 64 + cell) * CSD + qf);
    cv1[it] = *(const float4*)(cs + (size_t)(c0 + it * 64 + 32 + cell) * CSD + qf);
    bv[it] = t_load(Wg1 + (size_t)(c0 + it * 64) * H, H, t);
  }
  f32x4 z = {0.f, 0.f, 0.f, 0.f};
  f32x4 acc0 = z, acc1 = z;
#pragma unroll
  for (int it = 0; it < 3; it++) {
    int cb = it * 64;
    __syncthreads();
    u16x4 u0 = {f2bf(cv0[it].x), f2bf(cv0[it].y), f2bf(cv0[it].z), f2bf(cv0[it].w)};
    u16x4 u1 = {f2bf(cv1[it].x), f2bf(cv1[it].y), f2bf(cv1[it].z), f2bf(cv1[it].w)};
    *(u16x4*)&Csh[cell][qf] = u0;
    *(u16x4*)&Csh[cell + 32][qf] = u1;
    t_store(Bs, bv[it], t);
    __syncthreads();
    f32x4 dec0 = z, dec1 = z;
    {
      s16x8 a = *(const s16x8*)&Wd[ri * 16 + il][kg * 8];
      s16x8 b0 = *(const s16x8*)&Csh[cj * 32 + il][kg * 8];
      s16x8 b1 = *(const s16x8*)&Csh[cj * 32 + 16 + il][kg * 8];
      dec0 = __builtin_amdgcn_mfma_f32_16x16x32_bf16(a, b0, dec0, 0, 0, 0);
      dec1 = __builtin_amdgcn_mfma_f32_16x16x32_bf16(a, b1, dec1, 0, 0, 0);
    }
#pragma unroll
    for (int c = 0; c < 2; c++) {
      f32x4 dv = c ? dec1 : dec0;
      int kcol = cj * 32 + c * 16 + il;
      int mb = ri * 16 + kg * 4;
      float4 sv4;
      float* sp = (float*)&sv4;
#pragma unroll
      for (int r = 0; r < 4; r++) {
        float pre = dv[r] + bs_s[mb + r];
        float sg = 1.f / (1.f + __expf(-pre));
        sp[r] = sg;
        As[mb + r][kcol] = f2bf(sg);
      }
      *(float4*)(xr + (size_t)(c0 + cb + kcol) * N + g0 + mb) = sv4;
    }
    __syncthreads();
#pragma unroll
    for (int kk = 0; kk < 64; kk += 32) {
      s16x8 a = *(const s16x8*)&As[ri * 16 + il][kk + kg * 8];
      s16x8 b0 = *(const s16x8*)&Bs[cj * 32 + il][kk + kg * 8];
      s16x8 b1 = *(const s16x8*)&Bs[cj * 32 + 16 + il][kk + kg * 8];
      acc0 = __builtin_amdgcn_mfma_f32_16x16x32_bf16(a, b0, acc0, 0, 0, 0);
      acc1 = __builtin_amdgcn_mfma_f32_16x16x32_bf16(a, b1, acc1, 0, 0, 0);
    }
  }
  float* ob = outp + (size_t)blockIdx.y * NH;
#pragma unroll
  for (int c = 0; c < 2; c++) {
    f32x4 acc = c ? acc1 : acc0;
    int col = cj * 32 + c * 16 + il;
    int rbase = g0 + ri * 16 + kg * 4;
#pragma unroll
    for (int r = 0; r < 4; r++)
      ob[(size_t)(rbase + r) * H + col] = acc[r];
  }
}

// ---------------------------------------------------------------------------
// Reduce MMS partial h buffers -> h f32, fused with s_dst/s_src dots.
__global__ __launch_bounds__(256) void k_reduce_sd(const float* __restrict__ src,
                                                   const float* __restrict__ a,
                                                   float* __restrict__ h,
                                                   float* __restrict__ sdst,
                                                   float* __restrict__ ssrc) {
  int row = blockIdx.x * 4 + (threadIdx.x >> 6);
  int lane = threadIdx.x & 63;
  size_t off = (size_t)row * H + lane;
  float v = 0.f;
#pragma unroll
  for (int p = 0; p < MMS; p++) v += src[(size_t)p * NH + off];
  h[off] = v;
  float d1 = v * a[lane];
  float d2 = v * a[H + lane];
  for (int o = 32; o; o >>= 1) {
    d1 += __shfl_xor(d1, o);
    d2 += __shfl_xor(d2, o);
  }
  if (lane == 0) { sdst[row] = d1; ssrc[row] = d2; }
}

// ---------------------------------------------------------------------------
// MMS-way float4 partial reduce: dst = sum_p src[p].
__global__ __launch_bounds__(256) void k_reduce(const float4* __restrict__ src,
                                                float4* __restrict__ dst) {
  int idx = blockIdx.x * 256 + threadIdx.x;
  float4 v = {0, 0, 0, 0};
#pragma unroll
  for (int p = 0; p < MMS; p++) {
    float4 u = src[(size_t)p * (NH / 4) + idx];
    v.x += u.x; v.y += u.y; v.z += u.z; v.w += u.w;
  }
  dst[idx] = v;
}

// ---------------------------------------------------------------------------
// VAE + diffusion fusion; reduces SLICES hacc partials AND Z partials on load.
__global__ __launch_bounds__(256) void k_vae(const float* __restrict__ hacc,
                                             const float* __restrict__ zpart,
                                             const float* __restrict__ eps,
                                             const float* __restrict__ Wmu,
                                             const float* __restrict__ bmu,
                                             const float* __restrict__ Wlv,
                                             const float* __restrict__ blv,
                                             const float* __restrict__ Wd,
                                             const float* __restrict__ bd,
                                             float* __restrict__ mu_o,
                                             float* __restrict__ lv_o,
                                             float* __restrict__ cs_o,
                                             float* __restrict__ ie) {
  __shared__ float hs[16][65];
  __shared__ float zs[16][17];
  __shared__ float wmu_s[1024];
  __shared__ float wlv_s[1024];
  __shared__ float wd_s[2560];
  int t = threadIdx.x;
  int row0 = blockIdx.x * 16;
  {
    int rr = t >> 4, pp = t & 15;
    float zv = (pp < SLICES) ? zpart[(size_t)pp * N + row0 + rr] : 0.f;
    zv += __shfl_xor(zv, 1);
    zv += __shfl_xor(zv, 2);
    zv += __shfl_xor(zv, 4);
    zv += __shfl_xor(zv, 8);
    float zi = 1.0f / fmaxf(zv, 1e-30f);
    const float4* g4 = (const float4*)(hacc + (size_t)row0 * H);
    float4 v = {0, 0, 0, 0};
#pragma unroll
    for (int p = 0; p < SLICES; p++) {
      float4 u = g4[(size_t)p * (NH / 4) + t];
      v.x += u.x; v.y += u.y; v.z += u.z; v.w += u.w;
    }
    int c0 = (t & 15) * 4;
    float e0 = v.x * zi, e1 = v.y * zi, e2 = v.z * zi, e3 = v.w * zi;
    hs[rr][c0 + 0] = e0 > 0.f ? e0 : __expf(e0) - 1.f;
    hs[rr][c0 + 1] = e1 > 0.f ? e1 : __expf(e1) - 1.f;
    hs[rr][c0 + 2] = e2 > 0.f ? e2 : __expf(e2) - 1.f;
    hs[rr][c0 + 3] = e3 > 0.f ? e3 : __expf(e3) - 1.f;
  }
#pragma unroll
  for (int k = 0; k < 4; k++) {
    int lin = t + k * 256;
    wmu_s[lin] = Wmu[lin];
    wlv_s[lin] = Wlv[lin];
  }
#pragma unroll
  for (int k = 0; k < 10; k++) {
    int lin = t + k * 256;
    wd_s[lin] = Wd[lin];
  }
  __syncthreads();
  int r = t >> 4, kk = t & 15;
  float mu = bmu[kk], lv = blv[kk];
#pragma unroll 8
  for (int l = 0; l < 64; l++) {
    float hv = hs[r][l];
    mu += hv * wmu_s[l * 16 + kk];
    lv += hv * wlv_s[l * 16 + kk];
  }
  float zc = mu + eps[(size_t)(row0 + r) * CAUS + kk] * __expf(0.5f * lv);
  mu_o[(size_t)(row0 + r) * CAUS + kk] = mu;
  lv_o[(size_t)(row0 + r) * CAUS + kk] = lv;
  zs[r][kk] = zc;
  __syncthreads();
#pragma unroll
  for (int p = 0; p < 2; p++) {
    int lin = t + p * 256;
    int rr = lin >> 5, c = lin & 31;
    float acc = bd[c];
#pragma unroll 4
    for (int q = 0; q < 16; q++) acc += zs[rr][q] * wd_s[q * 32 + c];
#pragma unroll 8
    for (int l = 0; l < 64; l++) acc += hs[rr][l] * wd_s[(16 + l) * 32 + c];
    float v = fmaxf(acc, 0.f);
    cs_o[(size_t)(row0 + rr) * CSD + c] = v;
    ie[(size_t)(row0 + rr) * 96 + 64 + c] = v;
  }
}

// ---------------------------------------------------------------------------
// t2 = relu(sum_p h1part*dis) @ W2. 4 rows/block.
__global__ __launch_bounds__(256) void k_h1w2(const float* __restrict__ h1src,
                                              const float* __restrict__ dis,
                                              const float* __restrict__ W2,
                                              float* __restrict__ t2) {
  __shared__ float w2s[64 * 64];
  __shared__ float hs[4][65];
  int t = threadIdx.x;
  int row0 = blockIdx.x * 4;
#pragma unroll
  for (int k = 0; k < 16; k++) w2s[t + k * 256] = W2[t + k * 256];
  {
    int rr = t >> 6;
    size_t off = (size_t)row0 * H + t;
    float v = 0.f;
#pragma unroll
    for (int p = 0; p < SLICES; p++) v += h1src[(size_t)p * NH + off];
    hs[rr][t & 63] = fmaxf(v * dis[row0 + rr], 0.f);
  }
  __syncthreads();
  int r = t >> 6, f = t & 63;
  float acc = 0.f;
#pragma unroll 8
  for (int l = 0; l < 64; l++) acc += hs[r][l] * w2s[l * 64 + f];
  t2[(size_t)(row0 + r) * H + f] = acc;
}

// ---------------------------------------------------------------------------
// h2 = relu(sum_p h2part * dis); also writes ie[:, :64].
__global__ __launch_bounds__(256) void k_fin2(const float* __restrict__ h2src,
                                              const float* __restrict__ dis,
                                              float* __restrict__ h2,
                                              float* __restrict__ ie) {
  int idx = blockIdx.x * 256 + threadIdx.x;
  int row = idx >> 6, f = idx & 63;
  float v = 0.f;
#pragma unroll
  for (int p = 0; p < SLICES; p++) v += h2src[(size_t)p * NH + idx];
  v = fmaxf(v * dis[row], 0.f);
  h2[idx] = v;
  ie[(size_t)row * 96 + f] = v;
}

// ---------------------------------------------------------------------------
extern "C" void kernel_launch(void* const* d_in, const int* in_sizes, int n_in,
                              void* d_out, int out_size, void* d_ws, size_t ws_size,
                              hipStream_t stream) {
  const float* x    = (const float*)d_in[0];
  const int*   adj  = (const int*)d_in[1];
  const float* eps  = (const float*)d_in[2];
  const float* Wgat = (const float*)d_in[3];
  const float* agat = (const float*)d_in[4];
  const float* Wmu  = (const float*)d_in[5];
  const float* bmu  = (const float*)d_in[6];
  const float* Wlv  = (const float*)d_in[7];
  const float* blv  = (const float*)d_in[8];
  const float* Wdif = (const float*)d_in[9];
  const float* bdif = (const float*)d_in[10];
  const float* Wdec = (const float*)d_in[11];
  const float* bdec = (const float*)d_in[12];
  const float* Wg1  = (const float*)d_in[13];
  const float* Wg2  = (const float*)d_in[14];

  float* out = (float*)d_out;
  float* xr  = out;                       // (3072,3072)
  float* h2  = out + 9437184;             // (3072,64)
  float* ie  = out + 9633792;             // (3072,96)
  float* cs  = out + 9928704;             // (3072,32)
  float* muo = out + 10027008;            // (3072,16)
  float* lvo = out + 10076160;            // (3072,16)

  // Workspace (~18 MB of 256 MB)
  u64* packed = (u64*)d_ws;               // 3072*48 u64 = 1.18 MB
  float* wf    = (float*)d_ws + 294912;
  float* part  = wf;                      // MMS*NH f32 partials (reused)
  float* h     = part + (size_t)MMS * NH;
  float* t1    = h + NH;
  float* t2    = t1 + NH;
  float* sdst  = t2 + NH;
  float* ssrc  = sdst + N;
  float* dis   = ssrc + N;
  float* zpart = dis + N;                 // SLICES*N

  // 1: adjacency pack (768) + x^T@Wgat (1536 blocks, dbuf, upfront loads)
  k_mmpk<<<2304, 256, 0, stream>>>(x, Wgat, part, adj, packed, dis);
  // 2: reduce 16 partials -> h + attention dot products
  k_reduce_sd<<<768, 256, 0, stream>>>(part, agat, h, sdst, ssrc);
  // 3: GAT aggregation split-K (96x8, dbuf) -> part + zpart
  k_agg<1><<<dim3(96, SLICES), 256, 0, stream>>>(h, packed, sdst, ssrc, dis,
                                                 part, zpart);
  // 4: VAE epilogue (reduces part + zpart -> mu/lv/cs/ie-hi)
  k_vae<<<192, 256, 0, stream>>>(part, zpart, eps, Wmu, bmu, Wlv, blv,
                                 Wdif, bdif, muo, lvo, cs, ie);
  // 5: fused decoder + GCN GEMM (xr output + t1 partials)
  k_dec32<<<dim3(96, MMS), 256, 0, stream>>>(cs, Wdec, bdec, Wg1, xr, part);
  // 6: reduce 16 partials -> t1
  k_reduce<<<192, 256, 0, stream>>>((const float4*)part, (float4*)t1);
  // 7: GCN agg split-K on t1 -> part
  k_agg<0><<<dim3(96, SLICES), 256, 0, stream>>>(t1, packed, nullptr, nullptr,
                                                 dis, part, nullptr);
  // 8: h1 epilogue + @W2 -> t2
  k_h1w2<<<768, 256, 0, stream>>>(part, dis, Wg2, t2);
  // 9: GCN agg split-K on t2 -> part
  k_agg<0><<<dim3(96, SLICES), 256, 0, stream>>>(t2, packed, nullptr, nullptr,
                                                 dis, part, nullptr);
  // 10: final epilogue -> h2 + ie-lo
  k_fin2<<<768, 256, 0, stream>>>(part, dis, h2, ie);
}

// Round 16
// 99.264 us; speedup vs baseline: 1.0248x; 1.0248x over previous
//
#include <hip/hip_runtime.h>
#include <math.h>

#define N 3072
#define H 64
#define CAUS 16
#define CSD 32
#define GAT_ALPHA 0.35f
#define SLICES 8
#define JSL (N / SLICES)  // 384 (agg split)
#define MMS 16
#define JMM (N / MMS)     // 192 (mm/dec split)
#define NH (N * H)        // 196608
typedef unsigned long long u64;
typedef unsigned short u16;
typedef __attribute__((ext_vector_type(4))) float f32x4;
typedef __attribute__((ext_vector_type(8))) short s16x8;
struct alignas(8) u16x4 { u16 x, y, z, w; };
struct T4 { float4 r[4]; };

// f32 -> bf16 round-to-nearest-even
__device__ inline u16 f2bf(float f) {
  unsigned u = __builtin_bit_cast(unsigned, f);
  u += 0x7fffu + ((u >> 16) & 1u);
  return (u16)(u >> 16);
}

__device__ inline T4 t_load(const float* __restrict__ src, int ld, int t) {
  int k4 = (t >> 4) * 4, m4 = (t & 15) * 4;
  T4 o;
#pragma unroll
  for (int d = 0; d < 4; d++)
    o.r[d] = *(const float4*)(src + (size_t)(k4 + d) * ld + m4);
  return o;
}
__device__ inline void t_store(u16 (&dst)[64][72], const T4& v, int t) {
  int k4 = (t >> 4) * 4, m4 = (t & 15) * 4;
  u16x4 c0 = {f2bf(v.r[0].x), f2bf(v.r[1].x), f2bf(v.r[2].x), f2bf(v.r[3].x)};
  u16x4 c1 = {f2bf(v.r[0].y), f2bf(v.r[1].y), f2bf(v.r[2].y), f2bf(v.r[3].y)};
  u16x4 c2 = {f2bf(v.r[0].z), f2bf(v.r[1].z), f2bf(v.r[2].z), f2bf(v.r[3].z)};
  u16x4 c3 = {f2bf(v.r[0].w), f2bf(v.r[1].w), f2bf(v.r[2].w), f2bf(v.r[3].w)};
  *(u16x4*)&dst[m4 + 0][k4] = c0;
  *(u16x4*)&dst[m4 + 1][k4] = c1;
  *(u16x4*)&dst[m4 + 2][k4] = c2;
  *(u16x4*)&dst[m4 + 3][k4] = c3;
}

// ---------------------------------------------------------------------------
// Fused: blocks 0-1535 = x^T@Wgat GEMM (32-gene tiles, 16 K-slices, ALL K
// loads issued upfront); blocks 1536-2303 = adjacency pack (batched loads).
__global__ __launch_bounds__(256) void k_mmpk(const float* __restrict__ x,
                                              const float* __restrict__ Wgat,
                                              float* __restrict__ part,
                                              const int* __restrict__ adj,
                                              u64* __restrict__ packed,
                                              float* __restrict__ dis) {
  __shared__ u16 As[32][72];
  __shared__ u16 Bs[64][72];
  int bid = blockIdx.x, t = threadIdx.x;
  if (bid >= 1536) {  // ---- pack branch
    int row = (bid - 1536) * 4 + (t >> 6), lane = t & 63;
    const int* ar = adj + (size_t)row * N;
    int deg = 0;
    for (int w0 = 0; w0 < 48; w0 += 8) {
      int vals[8];
#pragma unroll
      for (int q = 0; q < 8; q++) vals[q] = ar[(w0 + q) * 64 + lane];
#pragma unroll
      for (int q = 0; q < 8; q++) {
        u64 m = __ballot(vals[q] > 0);
        if (lane == 0) packed[(size_t)row * 48 + w0 + q] = m;
        deg += (vals[q] > 0) ? 1 : 0;
      }
    }
    for (int off = 32; off; off >>= 1) deg += __shfl_xor(deg, off);
    if (lane == 0) dis[row] = rsqrtf((float)deg + 1.0f);
    return;
  }
  // ---- GEMM branch: out[m][n] = sum_{k in slice} x[k][m]*Wgat[k][n]
  int gx = bid % 96, sl = bid / 96;
  int g0 = gx * 32, c0 = sl * JMM;
  int w = t >> 6, l = t & 63, il = l & 15, kg = l >> 4;
  int ri = w & 1, cj = w >> 1;
  int ak = (t >> 3) * 2, am = (t & 7) * 4;
  // Issue ALL 3 K-iterations' loads upfront: one HBM-latency exposure/block.
  float4 a0[3], a1[3];
  T4 bv[3];
#pragma unroll
  for (int it = 0; it < 3; it++) {
    a0[it] = *(const float4*)(x + (size_t)(c0 + it * 64 + ak) * N + g0 + am);
    a1[it] = *(const float4*)(x + (size_t)(c0 + it * 64 + ak + 1) * N + g0 + am);
    bv[it] = t_load(Wgat + (size_t)(c0 + it * 64) * H, H, t);
  }
  f32x4 acc0 = {0.f, 0.f, 0.f, 0.f}, acc1 = {0.f, 0.f, 0.f, 0.f};
#pragma unroll
  for (int it = 0; it < 3; it++) {
    __syncthreads();
    As[am + 0][ak] = f2bf(a0[it].x); As[am + 1][ak] = f2bf(a0[it].y);
    As[am + 2][ak] = f2bf(a0[it].z); As[am + 3][ak] = f2bf(a0[it].w);
    As[am + 0][ak + 1] = f2bf(a1[it].x); As[am + 1][ak + 1] = f2bf(a1[it].y);
    As[am + 2][ak + 1] = f2bf(a1[it].z); As[am + 3][ak + 1] = f2bf(a1[it].w);
    t_store(Bs, bv[it], t);
    __syncthreads();
#pragma unroll
    for (int kk = 0; kk < 64; kk += 32) {
      s16x8 a = *(const s16x8*)&As[ri * 16 + il][kk + kg * 8];
      s16x8 b0 = *(const s16x8*)&Bs[cj * 32 + il][kk + kg * 8];
      s16x8 b1 = *(const s16x8*)&Bs[cj * 32 + 16 + il][kk + kg * 8];
      acc0 = __builtin_amdgcn_mfma_f32_16x16x32_bf16(a, b0, acc0, 0, 0, 0);
      acc1 = __builtin_amdgcn_mfma_f32_16x16x32_bf16(a, b1, acc1, 0, 0, 0);
    }
  }
  float* ob = part + (size_t)sl * NH;
#pragma unroll
  for (int c = 0; c < 2; c++) {
    f32x4 acc = c ? acc1 : acc0;
    int col = cj * 32 + c * 16 + il;
    int rbase = g0 + ri * 16 + kg * 4;
#pragma unroll
    for (int r = 0; r < 4; r++)
      ob[(size_t)(rbase + r) * H + col] = acc[r];
  }
}

// ---------------------------------------------------------------------------
// Split-K masked aggregation, 32-row tiles, grid (96,8).
template <int GAT>
__global__ __launch_bounds__(256) void k_agg(const float* __restrict__ hin,
                                             const u64* __restrict__ packed,
                                             const float* __restrict__ sdst,
                                             const float* __restrict__ ssrc,
                                             const float* __restrict__ dis,
                                             float* __restrict__ outp,
                                             float* __restrict__ zpart) {
  __shared__ u16 Ws[32][72];
  __shared__ u16 Hs[64][72];
  __shared__ float ssl[32];
  int t = threadIdx.x;
  int i0 = blockIdx.x * 32;
  int jbase = blockIdx.y * JSL;
  int w = t >> 6, l = t & 63, il = l & 15, kg = l >> 4;
  int ri = w & 1, cj = w >> 1;
  int r = t >> 3, jq = (t & 7) * 8;
  if (GAT && t < 32) ssl[t] = ssrc[i0 + t];
  __syncthreads();
  float sv = GAT ? ssl[r] : 0.f;
  float zacc = 0.f;
  f32x4 acc0 = {0.f, 0.f, 0.f, 0.f}, acc1 = {0.f, 0.f, 0.f, 0.f};

  auto gen_w = [&](int j0, float (&wv)[8]) {
    u64 wb = packed[(size_t)(i0 + r) * 48 + (j0 >> 6)];
    if (GAT) {
      const float4* s4p = (const float4*)(sdst + j0 + jq);
      float4 s0 = s4p[0], s1 = s4p[1];
      float sf[8] = {s0.x, s0.y, s0.z, s0.w, s1.x, s1.y, s1.z, s1.w};
#pragma unroll
      for (int q = 0; q < 8; q++) {
        float e = sv + sf[q];
        e = e > 0.f ? e : GAT_ALPHA * e;
        float ww = ((wb >> (jq + q)) & 1ULL) ? __expf(e) : 0.f;
        wv[q] = ww;
        zacc += ww;
      }
    } else {
      const float4* d4p = (const float4*)(dis + j0 + jq);
      float4 d0 = d4p[0], d1 = d4p[1];
      float df[8] = {d0.x, d0.y, d0.z, d0.w, d1.x, d1.y, d1.z, d1.w};
#pragma unroll
      for (int q = 0; q < 8; q++) {
        float cnt = (float)((wb >> (jq + q)) & 1ULL) +
                    ((i0 + r) == (j0 + jq + q) ? 1.f : 0.f);
        wv[q] = cnt * df[q];
      }
    }
  };

  T4 hv = t_load(hin + (size_t)jbase * H, H, t);
  float wv[8];
  gen_w(jbase, wv);
  for (int jb = 0; jb < JSL; jb += 64) {
    __syncthreads();
    t_store(Hs, hv, t);
    u16x4 w0 = {f2bf(wv[0]), f2bf(wv[1]), f2bf(wv[2]), f2bf(wv[3])};
    u16x4 w1 = {f2bf(wv[4]), f2bf(wv[5]), f2bf(wv[6]), f2bf(wv[7])};
    *(u16x4*)&Ws[r][jq] = w0;
    *(u16x4*)&Ws[r][jq + 4] = w1;
    if (jb + 64 < JSL) {
      hv = t_load(hin + (size_t)(jbase + jb + 64) * H, H, t);
      gen_w(jbase + jb + 64, wv);
    }
    __syncthreads();
#pragma unroll
    for (int kk = 0; kk < 64; kk += 32) {
      s16x8 a = *(const s16x8*)&Ws[ri * 16 + il][kk + kg * 8];
      s16x8 b0 = *(const s16x8*)&Hs[cj * 32 + il][kk + kg * 8];
      s16x8 b1 = *(const s16x8*)&Hs[cj * 32 + 16 + il][kk + kg * 8];
      acc0 = __builtin_amdgcn_mfma_f32_16x16x32_bf16(a, b0, acc0, 0, 0, 0);
      acc1 = __builtin_amdgcn_mfma_f32_16x16x32_bf16(a, b1, acc1, 0, 0, 0);
    }
  }
  if (GAT) {
    zacc += __shfl_xor(zacc, 1);
    zacc += __shfl_xor(zacc, 2);
    zacc += __shfl_xor(zacc, 4);
    if ((t & 7) == 0) zpart[(size_t)blockIdx.y * N + i0 + r] = zacc;
  }
  float* ob = outp + (size_t)blockIdx.y * NH;
#pragma unroll
  for (int c = 0; c < 2; c++) {
    f32x4 acc = c ? acc1 : acc0;
    int col = cj * 32 + c * 16 + il;
    int rbase = i0 + ri * 16 + kg * 4;
#pragma unroll
    for (int rr = 0; rr < 4; rr++)
      ob[(size_t)(rbase + rr) * H + col] = acc[rr];
  }
}

// ---------------------------------------------------------------------------
// Fused decoder + GCN GEMM: 32-gene tiles, grid (96, 16), upfront K-loads.
__global__ __launch_bounds__(256) void k_dec32(const float* __restrict__ cs,
                                               const float* __restrict__ Wdec,
                                               const float* __restrict__ bdec,
                                               const float* __restrict__ Wg1,
                                               float* __restrict__ xr,
                                               float* __restrict__ outp) {
  __shared__ u16 As[32][72];
  __shared__ u16 Bs[64][72];
  __shared__ u16 Wd[32][40];
  __shared__ u16 Csh[64][40];
  __shared__ float bs_s[32];
  int t = threadIdx.x;
  int g0 = blockIdx.x * 32;
  int c0 = blockIdx.y * JMM;
  int w = t >> 6, l = t & 63, il = l & 15, kg = l >> 4;
  int ri = w & 1, cj = w >> 1;
  {
    int q = t >> 3, m4 = (t & 7) * 4;
    float4 v = *(const float4*)(Wdec + (size_t)q * N + g0 + m4);
    Wd[m4 + 0][q] = f2bf(v.x); Wd[m4 + 1][q] = f2bf(v.y);
    Wd[m4 + 2][q] = f2bf(v.z); Wd[m4 + 3][q] = f2bf(v.w);
    if (t < 32) bs_s[t] = bdec[g0 + t];
  }
  int cell = t >> 3, qf = (t & 7) * 4;
  // Upfront loads for all 3 K-iterations.
  float4 cv0[3], cv1[3];
  T4 bv[3];
#pragma unroll
  for (int it = 0; it < 3; it++) {
    cv0[it] = *(const float4*)(cs + (size_t)(c0 + it * 64 + cell) * CSD + qf);
    cv1[it] = *(const float4*)(cs + (size_t)(c0 + it * 64 + 32 + cell) * CSD + qf);
    bv[it] = t_load(Wg1 + (size_t)(c0 + it * 64) * H, H, t);
  }
  f32x4 z = {0.f, 0.f, 0.f, 0.f};
  f32x4 acc0 = z, acc1 = z;
#pragma unroll
  for (int it = 0; it < 3; it++) {
    int cb = it * 64;
    __syncthreads();
    u16x4 u0 = {f2bf(cv0[it].x), f2bf(cv0[it].y), f2bf(cv0[it].z), f2bf(cv0[it].w)};
    u16x4 u1 = {f2bf(cv1[it].x), f2bf(cv1[it].y), f2bf(cv1[it].z), f2bf(cv1[it].w)};
    *(u16x4*)&Csh[cell][qf] = u0;
    *(u16x4*)&Csh[cell + 32][qf] = u1;
    t_store(Bs, bv[it], t);
    __syncthreads();
    f32x4 dec0 = z, dec1 = z;
    {
      s16x8 a = *(const s16x8*)&Wd[ri * 16 + il][kg * 8];
      s16x8 b0 = *(const s16x8*)&Csh[cj * 32 + il][kg * 8];
      s16x8 b1 = *(const s16x8*)&Csh[cj * 32 + 16 + il][kg * 8];
      dec0 = __builtin_amdgcn_mfma_f32_16x16x32_bf16(a, b0, dec0, 0, 0, 0);
      dec1 = __builtin_amdgcn_mfma_f32_16x16x32_bf16(a, b1, dec1, 0, 0, 0);
    }
#pragma unroll
    for (int c = 0; c < 2; c++) {
      f32x4 dv = c ? dec1 : dec0;
      int kcol = cj * 32 + c * 16 + il;
      int mb = ri * 16 + kg * 4;
      float4 sv4;
      float* sp = (float*)&sv4;
#pragma unroll
      for (int r = 0; r < 4; r++) {
        float pre = dv[r] + bs_s[mb + r];
        float sg = 1.f / (1.f + __expf(-pre));
        sp[r] = sg;
        As[mb + r][kcol] = f2bf(sg);
      }
      *(float4*)(xr + (size_t)(c0 + cb + kcol) * N + g0 + mb) = sv4;
    }
    __syncthreads();
#pragma unroll
    for (int kk = 0; kk < 64; kk += 32) {
      s16x8 a = *(const s16x8*)&As[ri * 16 + il][kk + kg * 8];
      s16x8 b0 = *(const s16x8*)&Bs[cj * 32 + il][kk + kg * 8];
      s16x8 b1 = *(const s16x8*)&Bs[cj * 32 + 16 + il][kk + kg * 8];
      acc0 = __builtin_amdgcn_mfma_f32_16x16x32_bf16(a, b0, acc0, 0, 0, 0);
      acc1 = __builtin_amdgcn_mfma_f32_16x16x32_bf16(a, b1, acc1, 0, 0, 0);
    }
  }
  float* ob = outp + (size_t)blockIdx.y * NH;
#pragma unroll
  for (int c = 0; c < 2; c++) {
    f32x4 acc = c ? acc1 : acc0;
    int col = cj * 32 + c * 16 + il;
    int rbase = g0 + ri * 16 + kg * 4;
#pragma unroll
    for (int r = 0; r < 4; r++)
      ob[(size_t)(rbase + r) * H + col] = acc[r];
  }
}

// ---------------------------------------------------------------------------
// Reduce MMS partial h buffers -> h f32, fused with s_dst/s_src dots.
__global__ __launch_bounds__(256) void k_reduce_sd(const float* __restrict__ src,
                                                   const float* __restrict__ a,
                                                   float* __restrict__ h,
                                                   float* __restrict__ sdst,
                                                   float* __restrict__ ssrc) {
  int row = blockIdx.x * 4 + (threadIdx.x >> 6);
  int lane = threadIdx.x & 63;
  size_t off = (size_t)row * H + lane;
  float v = 0.f;
#pragma unroll
  for (int p = 0; p < MMS; p++) v += src[(size_t)p * NH + off];
  h[off] = v;
  float d1 = v * a[lane];
  float d2 = v * a[H + lane];
  for (int o = 32; o; o >>= 1) {
    d1 += __shfl_xor(d1, o);
    d2 += __shfl_xor(d2, o);
  }
  if (lane == 0) { sdst[row] = d1; ssrc[row] = d2; }
}

// ---------------------------------------------------------------------------
// MMS-way float4 partial reduce: dst = sum_p src[p].
__global__ __launch_bounds__(256) void k_reduce(const float4* __restrict__ src,
                                                float4* __restrict__ dst) {
  int idx = blockIdx.x * 256 + threadIdx.x;
  float4 v = {0, 0, 0, 0};
#pragma unroll
  for (int p = 0; p < MMS; p++) {
    float4 u = src[(size_t)p * (NH / 4) + idx];
    v.x += u.x; v.y += u.y; v.z += u.z; v.w += u.w;
  }
  dst[idx] = v;
}

// ---------------------------------------------------------------------------
// VAE + diffusion fusion; reduces SLICES hacc partials AND Z partials on load.
__global__ __launch_bounds__(256) void k_vae(const float* __restrict__ hacc,
                                             const float* __restrict__ zpart,
                                             const float* __restrict__ eps,
                                             const float* __restrict__ Wmu,
                                             const float* __restrict__ bmu,
                                             const float* __restrict__ Wlv,
                                             const float* __restrict__ blv,
                                             const float* __restrict__ Wd,
                                             const float* __restrict__ bd,
                                             float* __restrict__ mu_o,
                                             float* __restrict__ lv_o,
                                             float* __restrict__ cs_o,
                                             float* __restrict__ ie) {
  __shared__ float hs[16][65];
  __shared__ float zs[16][17];
  __shared__ float wmu_s[1024];
  __shared__ float wlv_s[1024];
  __shared__ float wd_s[2560];
  int t = threadIdx.x;
  int row0 = blockIdx.x * 16;
  {
    int rr = t >> 4, pp = t & 15;
    float zv = (pp < SLICES) ? zpart[(size_t)pp * N + row0 + rr] : 0.f;
    zv += __shfl_xor(zv, 1);
    zv += __shfl_xor(zv, 2);
    zv += __shfl_xor(zv, 4);
    zv += __shfl_xor(zv, 8);
    float zi = 1.0f / fmaxf(zv, 1e-30f);
    const float4* g4 = (const float4*)(hacc + (size_t)row0 * H);
    float4 v = {0, 0, 0, 0};
#pragma unroll
    for (int p = 0; p < SLICES; p++) {
      float4 u = g4[(size_t)p * (NH / 4) + t];
      v.x += u.x; v.y += u.y; v.z += u.z; v.w += u.w;
    }
    int c0 = (t & 15) * 4;
    float e0 = v.x * zi, e1 = v.y * zi, e2 = v.z * zi, e3 = v.w * zi;
    hs[rr][c0 + 0] = e0 > 0.f ? e0 : __expf(e0) - 1.f;
    hs[rr][c0 + 1] = e1 > 0.f ? e1 : __expf(e1) - 1.f;
    hs[rr][c0 + 2] = e2 > 0.f ? e2 : __expf(e2) - 1.f;
    hs[rr][c0 + 3] = e3 > 0.f ? e3 : __expf(e3) - 1.f;
  }
#pragma unroll
  for (int k = 0; k < 4; k++) {
    int lin = t + k * 256;
    wmu_s[lin] = Wmu[lin];
    wlv_s[lin] = Wlv[lin];
  }
#pragma unroll
  for (int k = 0; k < 10; k++) {
    int lin = t + k * 256;
    wd_s[lin] = Wd[lin];
  }
  __syncthreads();
  int r = t >> 4, kk = t & 15;
  float mu = bmu[kk], lv = blv[kk];
#pragma unroll 8
  for (int l = 0; l < 64; l++) {
    float hv = hs[r][l];
    mu += hv * wmu_s[l * 16 + kk];
    lv += hv * wlv_s[l * 16 + kk];
  }
  float zc = mu + eps[(size_t)(row0 + r) * CAUS + kk] * __expf(0.5f * lv);
  mu_o[(size_t)(row0 + r) * CAUS + kk] = mu;
  lv_o[(size_t)(row0 + r) * CAUS + kk] = lv;
  zs[r][kk] = zc;
  __syncthreads();
#pragma unroll
  for (int p = 0; p < 2; p++) {
    int lin = t + p * 256;
    int rr = lin >> 5, c = lin & 31;
    float acc = bd[c];
#pragma unroll 4
    for (int q = 0; q < 16; q++) acc += zs[rr][q] * wd_s[q * 32 + c];
#pragma unroll 8
    for (int l = 0; l < 64; l++) acc += hs[rr][l] * wd_s[(16 + l) * 32 + c];
    float v = fmaxf(acc, 0.f);
    cs_o[(size_t)(row0 + rr) * CSD + c] = v;
    ie[(size_t)(row0 + rr) * 96 + 64 + c] = v;
  }
}

// ---------------------------------------------------------------------------
// t2 = relu(sum_p h1part*dis) @ W2. 4 rows/block.
__global__ __launch_bounds__(256) void k_h1w2(const float* __restrict__ h1src,
                                              const float* __restrict__ dis,
                                              const float* __restrict__ W2,
                                              float* __restrict__ t2) {
  __shared__ float w2s[64 * 64];
  __shared__ float hs[4][65];
  int t = threadIdx.x;
  int row0 = blockIdx.x * 4;
#pragma unroll
  for (int k = 0; k < 16; k++) w2s[t + k * 256] = W2[t + k * 256];
  {
    int rr = t >> 6;
    size_t off = (size_t)row0 * H + t;
    float v = 0.f;
#pragma unroll
    for (int p = 0; p < SLICES; p++) v += h1src[(size_t)p * NH + off];
    hs[rr][t & 63] = fmaxf(v * dis[row0 + rr], 0.f);
  }
  __syncthreads();
  int r = t >> 6, f = t & 63;
  float acc = 0.f;
#pragma unroll 8
  for (int l = 0; l < 64; l++) acc += hs[r][l] * w2s[l * 64 + f];
  t2[(size_t)(row0 + r) * H + f] = acc;
}

// ---------------------------------------------------------------------------
// h2 = relu(sum_p h2part * dis); also writes ie[:, :64].
__global__ __launch_bounds__(256) void k_fin2(const float* __restrict__ h2src,
                                              const float* __restrict__ dis,
                                              float* __restrict__ h2,
                                              float* __restrict__ ie) {
  int idx = blockIdx.x * 256 + threadIdx.x;
  int row = idx >> 6, f = idx & 63;
  float v = 0.f;
#pragma unroll
  for (int p = 0; p < SLICES; p++) v += h2src[(size_t)p * NH + idx];
  v = fmaxf(v * dis[row], 0.f);
  h2[idx] = v;
  ie[(size_t)row * 96 + f] = v;
}

// ---------------------------------------------------------------------------
extern "C" void kernel_launch(void* const* d_in, const int* in_sizes, int n_in,
                              void* d_out, int out_size, void* d_ws, size_t ws_size,
                              hipStream_t stream) {
  const float* x    = (const float*)d_in[0];
  const int*   adj  = (const int*)d_in[1];
  const float* eps  = (const float*)d_in[2];
  const float* Wgat = (const float*)d_in[3];
  const float* agat = (const float*)d_in[4];
  const float* Wmu  = (const float*)d_in[5];
  const float* bmu  = (const float*)d_in[6];
  const float* Wlv  = (const float*)d_in[7];
  const float* blv  = (const float*)d_in[8];
  const float* Wdif = (const float*)d_in[9];
  const float* bdif = (const float*)d_in[10];
  const float* Wdec = (const float*)d_in[11];
  const float* bdec = (const float*)d_in[12];
  const float* Wg1  = (const float*)d_in[13];
  const float* Wg2  = (const float*)d_in[14];

  float* out = (float*)d_out;
  float* xr  = out;                       // (3072,3072)
  float* h2  = out + 9437184;             // (3072,64)
  float* ie  = out + 9633792;             // (3072,96)
  float* cs  = out + 9928704;             // (3072,32)
  float* muo = out + 10027008;            // (3072,16)
  float* lvo = out + 10076160;            // (3072,16)

  // Workspace (~18 MB of 256 MB)
  u64* packed = (u64*)d_ws;               // 3072*48 u64 = 1.18 MB
  float* wf    = (float*)d_ws + 294912;
  float* part  = wf;                      // MMS*NH f32 partials (reused)
  float* h     = part + (size_t)MMS * NH;
  float* t1    = h + NH;
  float* t2    = t1 + NH;
  float* sdst  = t2 + NH;
  float* ssrc  = sdst + N;
  float* dis   = ssrc + N;
  float* zpart = dis + N;                 // SLICES*N

  // 1: fused x^T@Wgat (1536 blocks, upfront K-loads) + adjacency pack (768)
  k_mmpk<<<2304, 256, 0, stream>>>(x, Wgat, part, adj, packed, dis);
  // 2: reduce 16 partials -> h + attention dot products
  k_reduce_sd<<<768, 256, 0, stream>>>(part, agat, h, sdst, ssrc);
  // 3: GAT aggregation split-K (96x8) -> part + zpart
  k_agg<1><<<dim3(96, SLICES), 256, 0, stream>>>(h, packed, sdst, ssrc, dis,
                                                 part, zpart);
  // 4: VAE epilogue (reduces part + zpart -> mu/lv/cs/ie-hi)
  k_vae<<<192, 256, 0, stream>>>(part, zpart, eps, Wmu, bmu, Wlv, blv,
                                 Wdif, bdif, muo, lvo, cs, ie);
  // 5: fused decoder + GCN GEMM (xr output + t1 partials, upfront K-loads)
  k_dec32<<<dim3(96, MMS), 256, 0, stream>>>(cs, Wdec, bdec, Wg1, xr, part);
  // 6: reduce 16 partials -> t1
  k_reduce<<<192, 256, 0, stream>>>((const float4*)part, (float4*)t1);
  // 7: GCN agg split-K on t1 -> part
  k_agg<0><<<dim3(96, SLICES), 256, 0, stream>>>(t1, packed, nullptr, nullptr,
                                                 dis, part, nullptr);
  // 8: h1 epilogue + @W2 -> t2
  k_h1w2<<<768, 256, 0, stream>>>(part, dis, Wg2, t2);
  // 9: GCN agg split-K on t2 -> part
  k_agg<0><<<dim3(96, SLICES), 256, 0, stream>>>(t2, packed, nullptr, nullptr,
                                                 dis, part, nullptr);
  // 10: final epilogue -> h2 + ie-lo
  k_fin2<<<768, 256, 0, stream>>>(part, dis, h2, ie);
}